// Round 8
// baseline (499.518 us; speedup 1.0000x reference)
//
#include <hip/hip_runtime.h>

constexpr int NN  = 50000;   // nodes
constexpr int NE  = 800000;  // edges

using frag_ab = __attribute__((ext_vector_type(8))) short;  // 8 bf16
using frag_cd = __attribute__((ext_vector_type(4))) float;  // 4 fp32

__device__ __forceinline__ unsigned short f2bf(float f) {   // RNE
    union { float f; unsigned u; } v; v.f = f;
    unsigned r = v.u + 0x7FFFu + ((v.u >> 16) & 1u);
    return (unsigned short)(r >> 16);
}
__device__ __forceinline__ float bflo(unsigned u) {
    union { unsigned u; float f; } v; v.u = u << 16; return v.f;
}
__device__ __forceinline__ float bfhi(unsigned u) {
    union { unsigned u; float f; } v; v.u = u & 0xFFFF0000u; return v.f;
}
__device__ __forceinline__ float bfs(unsigned short u) {
    union { unsigned u; float f; } v; v.u = (unsigned)u << 16; return v.f;
}
__device__ __forceinline__ unsigned packbf(float a, float b) {       // RNE
    return (unsigned)f2bf(a) | ((unsigned)f2bf(b) << 16);
}
__device__ __forceinline__ unsigned packbf_fast(float a, float b) {  // round-half-up
    union { float f; unsigned u; } ua, ub; ua.f = a; ub.f = b;
    return ((ua.u + 0x8000u) >> 16) | ((ub.u + 0x8000u) & 0xFFFF0000u);
}

enum { EPI_LAYER = 1, EPI_PQBF = 2 };

// ---------------------------------------------------------------------------
// MFMA bf16 GEMM. Block: 64 rows x 128 cols, 4 waves, BK=64.
// ---------------------------------------------------------------------------
template<int EPI>
__launch_bounds__(256, 4)
__global__ void mfma_gemm_k(const unsigned short* __restrict__ A0,
                            const unsigned short* __restrict__ A1,
                            int lda, int kSplit,
                            const unsigned short* __restrict__ Wt,
                            const float* __restrict__ bias,
                            unsigned short* __restrict__ Cbf, int ldc,
                            const unsigned short* __restrict__ residbf,
                            int M, int K)
{
    __shared__ __align__(16) unsigned short As[64][72];    // [row][k], pad 8
    __shared__ __align__(16) unsigned short Ws[128][72];   // [n][k],  pad 8
    __shared__ float bs[128];
    __shared__ float part[(EPI == EPI_LAYER) ? 64 : 1][17];
    __shared__ float rinv[(EPI == EPI_LAYER) ? 64 : 1];

    const int t  = threadIdx.x;
    const int by = blockIdx.y;
    Wt   += (size_t)by * 128 * K;
    bias += (size_t)by * 128;
    if constexpr (EPI == EPI_PQBF) Cbf += (size_t)by * 128;
    const int m0 = blockIdx.x * 64;

    if (t < 128) bs[t] = bias[t];

    const int wv = t >> 6, l = t & 63, lq = l >> 4, lm = l & 15;
    frag_cd acc[8];
#pragma unroll
    for (int tb = 0; tb < 8; ++tb) acc[tb] = (frag_cd){0.f, 0.f, 0.f, 0.f};

    for (int kt = 0; kt < K; kt += 64) {
        const unsigned short* Asrc = (kt < kSplit) ? A0 : A1;
        const int kcol = (kt < kSplit) ? kt : kt - kSplit;
#pragma unroll
        for (int p = 0; p < 2; ++p) {
            int idx = p * 256 + t;            // 512 uint4 = 64 x 64 bf16
            int row = idx >> 3, c4 = idx & 7;
            int gm = m0 + row;
            uint4 v = make_uint4(0, 0, 0, 0);
            if (gm < M) v = *(const uint4*)&Asrc[(size_t)gm * lda + kcol + c4 * 8];
            *(uint4*)&As[row][c4 * 8] = v;
        }
#pragma unroll
        for (int p = 0; p < 4; ++p) {
            int idx = p * 256 + t;            // 1024 uint4 = 128 x 64 bf16
            int n = idx >> 3, c4 = idx & 7;
            *(uint4*)&Ws[n][c4 * 8] = *(const uint4*)&Wt[(size_t)n * K + kt + c4 * 8];
        }
        __syncthreads();
#pragma unroll
        for (int kb = 0; kb < 2; ++kb) {
            frag_ab af = *(const frag_ab*)&As[wv * 16 + lm][kb * 32 + lq * 8];
#pragma unroll
            for (int tb = 0; tb < 8; ++tb) {
                frag_ab bf = *(const frag_ab*)&Ws[tb * 16 + lm][kb * 32 + lq * 8];
                acc[tb] = __builtin_amdgcn_mfma_f32_16x16x32_bf16(af, bf, acc[tb], 0, 0, 0);
            }
        }
        __syncthreads();
    }

    if constexpr (EPI == EPI_LAYER) {
        float sq[4] = {0.f, 0.f, 0.f, 0.f};
#pragma unroll
        for (int tb = 0; tb < 8; ++tb) {
            float b = bs[tb * 16 + lm];
#pragma unroll
            for (int r = 0; r < 4; ++r) {
                acc[tb][r] += b;
                sq[r] += acc[tb][r] * acc[tb][r];
            }
        }
#pragma unroll
        for (int r = 0; r < 4; ++r) part[wv * 16 + lq * 4 + r][lm] = sq[r];
        __syncthreads();
        if (t < 64) {
            float s = 0.f;
#pragma unroll
            for (int c = 0; c < 16; ++c) s += part[t][c];
            rinv[t] = 1.0f / fmaxf(sqrtf(s), 1e-12f);
        }
        __syncthreads();
#pragma unroll
        for (int r = 0; r < 4; ++r) {
            int gr = m0 + wv * 16 + lq * 4 + r;
            if (gr >= M) continue;
            float ri = rinv[wv * 16 + lq * 4 + r];
#pragma unroll
            for (int tb = 0; tb < 8; ++tb) {
                int col = tb * 16 + lm;
                float o = bfs(residbf[(size_t)gr * 128 + col]) +
                          fmaxf(acc[tb][r], 0.f) * ri;
                Cbf[(size_t)gr * 128 + col] = f2bf(o);
            }
        }
    } else {
#pragma unroll
        for (int r = 0; r < 4; ++r) {
            int gr = m0 + wv * 16 + lq * 4 + r;
            if (gr >= M) continue;
#pragma unroll
            for (int tb = 0; tb < 8; ++tb) {
                int col = tb * 16 + lm;
                Cbf[(size_t)gr * ldc + col] = f2bf(acc[tb][r] + bs[col]);
            }
        }
    }
}

// ---------------------------------------------------------------------------
// CSR construction -> packed pk[pos]={src,dst,eid,0} + compact srt[pos]=src
// ---------------------------------------------------------------------------
__global__ void deg_k(const int* __restrict__ dst, int* __restrict__ deg) {
    int e = blockIdx.x * 256 + threadIdx.x;
    if (e < NE) atomicAdd(&deg[dst[e]], 1);
}

__global__ void scan1_k(const int* __restrict__ deg, int* __restrict__ rp,
                        int* __restrict__ bsum) {
    __shared__ int sh[512];
    int tid = threadIdx.x;
    int i = blockIdx.x * 512 + tid;
    int v = (i < NN) ? deg[i] : 0;
    sh[tid] = v;
    __syncthreads();
    for (int ofs = 1; ofs < 512; ofs <<= 1) {
        int x = (tid >= ofs) ? sh[tid - ofs] : 0;
        __syncthreads();
        sh[tid] += x;
        __syncthreads();
    }
    if (i < NN) rp[i] = sh[tid] - v;
    if (tid == 511) bsum[blockIdx.x] = sh[511];
}

__global__ void scan2_k(int* __restrict__ bsum, int nb) {
    __shared__ int sh[128];
    int tid = threadIdx.x;
    int v = (tid < nb) ? bsum[tid] : 0;
    sh[tid] = v;
    __syncthreads();
    for (int ofs = 1; ofs < 128; ofs <<= 1) {
        int x = (tid >= ofs) ? sh[tid - ofs] : 0;
        __syncthreads();
        sh[tid] += x;
        __syncthreads();
    }
    if (tid < nb) bsum[tid] = sh[tid] - v;
}

__global__ void scan3_k(int* __restrict__ rp, const int* __restrict__ bsum,
                        const int* __restrict__ deg, float* __restrict__ invd) {
    int i = blockIdx.x * 512 + threadIdx.x;
    if (i < NN) {
        rp[i] += bsum[blockIdx.x];
        int d = deg[i];
        invd[i] = 1.0f / (float)(d > 1 ? d : 1);
    }
    if (i == NN) rp[NN] = NE;
}

__global__ void fill_k(const int* __restrict__ src, const int* __restrict__ dst,
                       const int* __restrict__ rp, int* __restrict__ cnt,
                       int4* __restrict__ pk, int* __restrict__ srt) {
    int e = blockIdx.x * 256 + threadIdx.x;
    if (e < NE) {
        int s = src[e];
        int d = dst[e];
        int pos = rp[d] + atomicAdd(&cnt[d], 1);
        pk[pos]  = make_int4(s, d, e, 0);
        srt[pos] = s;
    }
}

// ---------------------------------------------------------------------------
// Mean aggregation, one WAVE per node. 32 lanes x 8 B per row, wave halves
// alternate rows => 1 VMEM instr / 2 rows; 8-pair unroll => 16 rows in flight
// (covers the mean-degree-16 node in one issue batch).
// ---------------------------------------------------------------------------
__launch_bounds__(256, 8)
__global__ void agg_k(const unsigned short* __restrict__ hbf,
                      const int* __restrict__ rp, const int* __restrict__ srt,
                      const float* __restrict__ invd,
                      unsigned short* __restrict__ cbf) {
    int gw   = (blockIdx.x * 256 + threadIdx.x) >> 6;   // node = global wave id
    if (gw >= NN) return;
    const int lane = threadIdx.x & 63;
    const int half = lane >> 5;          // which neighbor of the pair
    const int hl   = lane & 31;          // feature group: 4 feats (8 B)
    const int b = rp[gw], e = rp[gw + 1];
    float a0 = 0.f, a1 = 0.f, a2 = 0.f, a3 = 0.f;

    int p = b;
    for (; p + 16 <= e; p += 16) {       // 8 pairs, 16 rows in flight
        int sidx[8];
#pragma unroll
        for (int u = 0; u < 8; ++u) sidx[u] = srt[p + u * 2 + half];
        uint2 uu[8];
#pragma unroll
        for (int u = 0; u < 8; ++u)
            uu[u] = *(const uint2*)&hbf[(size_t)sidx[u] * 128 + hl * 4];
#pragma unroll
        for (int u = 0; u < 8; ++u) {
            a0 += bflo(uu[u].x); a1 += bfhi(uu[u].x);
            a2 += bflo(uu[u].y); a3 += bfhi(uu[u].y);
        }
    }
    for (; p + 2 <= e; p += 2) {         // single pair
        int s = srt[p + half];
        uint2 u = *(const uint2*)&hbf[(size_t)s * 128 + hl * 4];
        a0 += bflo(u.x); a1 += bfhi(u.x);
        a2 += bflo(u.y); a3 += bfhi(u.y);
    }
    if (p < e && half == 0) {            // odd-degree tail (half 0 only)
        int s = srt[p];
        uint2 u = *(const uint2*)&hbf[(size_t)s * 128 + hl * 4];
        a0 += bflo(u.x); a1 += bfhi(u.x);
        a2 += bflo(u.y); a3 += bfhi(u.y);
    }
    // combine halves
    a0 += __shfl_xor(a0, 32, 64);
    a1 += __shfl_xor(a1, 32, 64);
    a2 += __shfl_xor(a2, 32, 64);
    a3 += __shfl_xor(a3, 32, 64);

    float iv = invd[gw];
    if (half == 0) {
        uint2 r = make_uint2(packbf(a0 * iv, a1 * iv), packbf(a2 * iv, a3 * iv));
        *(uint2*)&cbf[(size_t)gw * 128 + hl * 4] = r;
    }
}

// ---------------------------------------------------------------------------
// Prep (merged with x->bf16 cast):
//   i in [0, 400000)           : xbf cast (8 floats per thread)
//   then Wct[4][128n][256k]; Wefft[256n][128k]; W1tg[64n][128k]; beff; Wembt.
// ---------------------------------------------------------------------------
constexpr int PREP_X    = 400000;                 // NN*64/8
constexpr int PREP_WCT  = PREP_X + 131072;
constexpr int PREP_WEFF = PREP_WCT + 32768;
constexpr int PREP_W1   = PREP_WEFF + 8192;
constexpr int PREP_BEFF = PREP_W1 + 256;
constexpr int PREP_WEMB = PREP_BEFF + 8192;

__global__ void prep_k(const float* __restrict__ x, unsigned short* __restrict__ xbf,
                       const float* __restrict__ Wconv, const float* __restrict__ W0,
                       const float* __restrict__ b0, const float* __restrict__ W1,
                       const float* __restrict__ Wemb,
                       unsigned short* __restrict__ Wct,
                       unsigned short* __restrict__ Wefft,
                       float* __restrict__ beff, unsigned short* __restrict__ W1tg,
                       unsigned short* __restrict__ Wembt) {
    int i = blockIdx.x * 256 + threadIdx.x;
    if (i < PREP_X) {
        float4 a = *(const float4*)&x[(size_t)i * 8];
        float4 b = *(const float4*)&x[(size_t)i * 8 + 4];
        uint4 o = make_uint4(packbf(a.x, a.y), packbf(a.z, a.w),
                             packbf(b.x, b.y), packbf(b.z, b.w));
        *(uint4*)&xbf[(size_t)i * 8] = o;
    } else if (i < PREP_WCT) {
        int j = i - PREP_X;
        int lyr = j >> 15, r = j & 32767, n = r >> 8, k = r & 255;
        Wct[j] = f2bf(Wconv[(size_t)lyr * 32768 + k * 128 + n]);
    } else if (i < PREP_WEFF) {
        int j = i - PREP_WCT, n = j >> 7, k = j & 127;
        float v = (n < 128) ? W0[k * 128 + n] : W0[(128 + k) * 128 + (n - 128)];
        Wefft[j] = f2bf(v);
    } else if (i < PREP_W1) {
        int j = i - PREP_WEFF, n = j >> 7, k = j & 127;
        W1tg[j] = f2bf(W1[k * 64 + n]);
    } else if (i < PREP_BEFF) {
        int j = i - PREP_W1;
        beff[j] = (j < 128) ? b0[j] : 0.f;
    } else if (i < PREP_WEMB) {
        int j = i - PREP_BEFF, n = j >> 6, k = j & 63;
        Wembt[j] = f2bf(Wemb[k * 128 + n]);
    }
}

// ---------------------------------------------------------------------------
// Fused edge readout (MFMA), CSR order, 64 edges/block, single barrier,
// in-register MLP2 (shfl reduce). LDS 35 KB -> 4 blocks/CU.
// blockOff allows splitting the edge range across dispatches.
// ---------------------------------------------------------------------------
__launch_bounds__(256, 4)
__global__ void edge_mlp_k(const unsigned short* __restrict__ pq,
                           const int4* __restrict__ pk, int blockOff,
                           const unsigned short* __restrict__ W1tg,
                           const float* __restrict__ b1,
                           const float* __restrict__ W2, const float* __restrict__ b2,
                           float* __restrict__ out)
{
    __shared__ __align__(16) unsigned short E0s[64][136];  // 17408 B
    __shared__ __align__(16) unsigned short W1s[64][136];  // 17408 B
    __shared__ int ee[64];
    const int t = threadIdx.x;
    const int p0 = (blockIdx.x + blockOff) * 64;

    // stage W1: 64 rows x 128 ushorts = 1024 uint4 (4 per thread)
#pragma unroll
    for (int p = 0; p < 4; ++p) {
        int i4 = p * 256 + t;                 // 0..1023
        int row = i4 >> 4;                    // 16 uint4 per row -> 0..63
        int c4  = i4 & 15;
        *(uint4*)&W1s[row][c4 * 8] = ((const uint4*)W1tg)[i4];
    }

    // phase 1: e0 = relu(p[src] + q[dst]) -> E0s bf16 (4 threads/edge)
    {
        const int ei = t >> 2;
        const int fs = (t & 3) * 32;
        int4 pkv = pk[p0 + ei];
        if ((t & 3) == 0) ee[ei] = pkv.z;
        const unsigned short* pr = pq + (size_t)pkv.x * 256 + fs;
        const unsigned short* qr = pq + (size_t)pkv.y * 256 + 128 + fs;
#pragma unroll
        for (int j = 0; j < 4; ++j) {
            uint4 a = *(const uint4*)(pr + j * 8);
            uint4 b = *(const uint4*)(qr + j * 8);
            uint4 r;
            r.x = packbf_fast(fmaxf(bflo(a.x) + bflo(b.x), 0.f),
                              fmaxf(bfhi(a.x) + bfhi(b.x), 0.f));
            r.y = packbf_fast(fmaxf(bflo(a.y) + bflo(b.y), 0.f),
                              fmaxf(bfhi(a.y) + bfhi(b.y), 0.f));
            r.z = packbf_fast(fmaxf(bflo(a.z) + bflo(b.z), 0.f),
                              fmaxf(bfhi(a.z) + bfhi(b.z), 0.f));
            r.w = packbf_fast(fmaxf(bflo(a.w) + bflo(b.w), 0.f),
                              fmaxf(bfhi(a.w) + bfhi(b.w), 0.f));
            *(uint4*)&E0s[ei][fs + j * 8] = r;
        }
    }
    __syncthreads();                 // single barrier

    // phase 2: MFMA. wave wv: edges [16wv,16wv+16) x 64 outs.
    const int wv = t >> 6, l = t & 63, lq = l >> 4, lm = l & 15;
    frag_cd acc[4];
#pragma unroll
    for (int tb = 0; tb < 4; ++tb) acc[tb] = (frag_cd){0.f, 0.f, 0.f, 0.f};
    const int erow = wv * 16 + lm;
#pragma unroll
    for (int kb = 0; kb < 4; ++kb) {
        frag_ab af = *(const frag_ab*)&E0s[erow][kb * 32 + lq * 8];
#pragma unroll
        for (int tb = 0; tb < 4; ++tb) {
            frag_ab bf = *(const frag_ab*)&W1s[tb * 16 + lm][kb * 32 + lq * 8];
            acc[tb] = __builtin_amdgcn_mfma_f32_16x16x32_bf16(af, bf, acc[tb], 0, 0, 0);
        }
    }

    // phase 3: in-register MLP2 (b1/W2 direct from global, L2-resident)
    float b1v[4], w20[4], w21[4];
#pragma unroll
    for (int tb = 0; tb < 4; ++tb) {
        int o = tb * 16 + lm;
        b1v[tb] = b1[o];
        w20[tb] = W2[o * 2];
        w21[tb] = W2[o * 2 + 1];
    }
    const float bo0 = b2[0], bo1 = b2[1];
#pragma unroll
    for (int r = 0; r < 4; ++r) {
        float s0 = 0.f, s1 = 0.f;
#pragma unroll
        for (int tb = 0; tb < 4; ++tb) {
            float e1 = fmaxf(acc[tb][r] + b1v[tb], 0.f);
            s0 += e1 * w20[tb];
            s1 += e1 * w21[tb];
        }
#pragma unroll
        for (int m = 1; m < 16; m <<= 1) {   // reduce over lm
            s0 += __shfl_xor(s0, m, 16);
            s1 += __shfl_xor(s1, m, 16);
        }
        if (lm == 0) {
            int e = wv * 16 + lq * 4 + r;
            *(float2*)&out[(size_t)ee[e] * 2] = make_float2(s0 + bo0, s1 + bo1);
        }
    }
}

// ---------------------------------------------------------------------------
extern "C" void kernel_launch(void* const* d_in, const int* in_sizes, int n_in,
                              void* d_out, int out_size, void* d_ws, size_t ws_size,
                              hipStream_t stream)
{
    const float* x    = (const float*)d_in[0];
    const int*   esrc = (const int*)  d_in[1];
    const int*   edst = (const int*)  d_in[2];
    const float* Wemb  = (const float*)d_in[5];
    const float* bemb  = (const float*)d_in[6];
    const float* Wconv = (const float*)d_in[7];
    const float* bconv = (const float*)d_in[8];
    const float* Wm0   = (const float*)d_in[9];
    const float* bm0   = (const float*)d_in[10];
    const float* Wm1   = (const float*)d_in[11];
    const float* bm1   = (const float*)d_in[12];
    const float* Wm2   = (const float*)d_in[13];
    const float* bm2   = (const float*)d_in[14];
    float* out = (float*)d_out;

    char* ws = (char*)d_ws;
    size_t off = 0;
    auto alloc = [&](size_t bytes) -> void* {
        void* p = ws + off;
        off = (off + bytes + 255) & ~(size_t)255;
        return p;
    };
    unsigned short* h0bf = (unsigned short*)alloc((size_t)NN * 128 * 2);
    unsigned short* h1bf = (unsigned short*)alloc((size_t)NN * 128 * 2);
    unsigned short* cbf  = (unsigned short*)alloc((size_t)NN * 128 * 2);
    unsigned short* pqb  = (unsigned short*)alloc((size_t)NN * 256 * 2);
    unsigned short* xbf  = (unsigned short*)alloc((size_t)NN * 64 * 2);
    unsigned short* Wct   = (unsigned short*)alloc(4 * 128 * 256 * 2);
    unsigned short* Wefft = (unsigned short*)alloc(256 * 128 * 2);
    float*          beff  = (float*)alloc(256 * 4);
    unsigned short* W1tg  = (unsigned short*)alloc(64 * 128 * 2);
    unsigned short* Wembt = (unsigned short*)alloc(128 * 64 * 2);
    int*   deg  = (int*)alloc((size_t)NN * 4);
    int*   rp   = (int*)alloc((size_t)(NN + 1) * 4);
    int*   cnt  = (int*)alloc((size_t)NN * 4);
    float* invd = (float*)alloc((size_t)NN * 4);
    int*   bsum = (int*)alloc(512);
    int4*  pk   = (int4*)alloc((size_t)NE * 16);
    int*   srt  = (int*)alloc((size_t)NE * 4);
    (void)ws_size; (void)in_sizes; (void)n_in; (void)out_size;

    hipMemsetAsync(deg, 0, (size_t)NN * 4, stream);
    hipMemsetAsync(cnt, 0, (size_t)NN * 4, stream);

    // cast + weight prep (merged)
    prep_k<<<(PREP_WEMB + 255) / 256, 256, 0, stream>>>(
        x, xbf, Wconv, Wm0, bm0, Wm1, Wemb, Wct, Wefft, beff, W1tg, Wembt);

    // CSR build (packed + compact srt)
    deg_k  <<<(NE + 255) / 256, 256, 0, stream>>>(edst, deg);
    scan1_k<<<(NN + 511) / 512, 512, 0, stream>>>(deg, rp, bsum);
    scan2_k<<<1, 128, 0, stream>>>(bsum, (NN + 511) / 512);
    scan3_k<<<(NN + 511) / 512, 512, 0, stream>>>(rp, bsum, deg, invd);
    fill_k <<<(NE + 255) / 256, 256, 0, stream>>>(esrc, edst, rp, cnt, pk, srt);

    // h0 = bf16(x @ Wemb + bemb) via MFMA
    mfma_gemm_k<EPI_PQBF><<<dim3((NN + 63) / 64, 1), 256, 0, stream>>>(
        xbf, nullptr, 64, 1 << 30, Wembt, bemb, h0bf, 128, nullptr, NN, 64);

    // 4 SAGE layers (MFMA, bf16 residual)
    unsigned short* hcbf = h0bf; unsigned short* hnbf = h1bf;
    for (int l = 0; l < 4; ++l) {
        agg_k<<<(NN + 3) / 4, 256, 0, stream>>>(hcbf, rp, srt, invd, cbf);
        mfma_gemm_k<EPI_LAYER><<<dim3((NN + 63) / 64, 1), 256, 0, stream>>>(
            hcbf, cbf, 128, 128, Wct + (size_t)l * 128 * 256,
            bconv + (size_t)l * 128, hnbf, 128, hcbf, NN, 256);
        unsigned short* tb = hcbf; hcbf = hnbf; hnbf = tb;
    }
    // after 4 layers: hcbf == h0bf

    // pq = bf16(h @ Weff + beff)  [NN][256]
    mfma_gemm_k<EPI_PQBF><<<dim3((NN + 63) / 64, 2), 256, 0, stream>>>(
        hcbf, nullptr, 128, 1 << 30, Wefft, beff, pqb, 256, nullptr, NN, 128);

    // fused edge readout, split into 2 half-range dispatches (profiling
    // visibility + tail overlap); same total work.
    constexpr int HALF_BLOCKS = NE / 64 / 2;     // 6250
    edge_mlp_k<<<HALF_BLOCKS, 256, 0, stream>>>(pqb, pk, 0,
                                                W1tg, bm1, Wm2, bm2, out);
    edge_mlp_k<<<HALF_BLOCKS, 256, 0, stream>>>(pqb, pk, HALF_BLOCKS,
                                                W1tg, bm1, Wm2, bm2, out);
}

// Round 9
// 494.695 us; speedup vs baseline: 1.0097x; 1.0097x over previous
//
#include <hip/hip_runtime.h>

constexpr int NN  = 50000;   // nodes
constexpr int NE  = 800000;  // edges

using frag_ab = __attribute__((ext_vector_type(8))) short;  // 8 bf16
using frag_cd = __attribute__((ext_vector_type(4))) float;  // 4 fp32

__device__ __forceinline__ unsigned short f2bf(float f) {   // RNE
    union { float f; unsigned u; } v; v.f = f;
    unsigned r = v.u + 0x7FFFu + ((v.u >> 16) & 1u);
    return (unsigned short)(r >> 16);
}
__device__ __forceinline__ float bflo(unsigned u) {
    union { unsigned u; float f; } v; v.u = u << 16; return v.f;
}
__device__ __forceinline__ float bfhi(unsigned u) {
    union { unsigned u; float f; } v; v.u = u & 0xFFFF0000u; return v.f;
}
__device__ __forceinline__ float bfs(unsigned short u) {
    union { unsigned u; float f; } v; v.u = (unsigned)u << 16; return v.f;
}
__device__ __forceinline__ unsigned packbf(float a, float b) {       // RNE
    return (unsigned)f2bf(a) | ((unsigned)f2bf(b) << 16);
}
__device__ __forceinline__ unsigned packbf_fast(float a, float b) {  // round-half-up
    union { float f; unsigned u; } ua, ub; ua.f = a; ub.f = b;
    return ((ua.u + 0x8000u) >> 16) | ((ub.u + 0x8000u) & 0xFFFF0000u);
}

enum { EPI_LAYER = 1, EPI_PQBF = 2 };

// ---------------------------------------------------------------------------
// MFMA bf16 GEMM. Block: 64 rows x 128 cols, 4 waves, BK=64.
// ---------------------------------------------------------------------------
template<int EPI>
__launch_bounds__(256, 4)
__global__ void mfma_gemm_k(const unsigned short* __restrict__ A0,
                            const unsigned short* __restrict__ A1,
                            int lda, int kSplit,
                            const unsigned short* __restrict__ Wt,
                            const float* __restrict__ bias,
                            unsigned short* __restrict__ Cbf, int ldc,
                            const unsigned short* __restrict__ residbf,
                            int M, int K)
{
    __shared__ __align__(16) unsigned short As[64][72];    // [row][k], pad 8
    __shared__ __align__(16) unsigned short Ws[128][72];   // [n][k],  pad 8
    __shared__ float bs[128];
    __shared__ float part[(EPI == EPI_LAYER) ? 64 : 1][17];
    __shared__ float rinv[(EPI == EPI_LAYER) ? 64 : 1];

    const int t  = threadIdx.x;
    const int by = blockIdx.y;
    Wt   += (size_t)by * 128 * K;
    bias += (size_t)by * 128;
    if constexpr (EPI == EPI_PQBF) Cbf += (size_t)by * 128;
    const int m0 = blockIdx.x * 64;

    if (t < 128) bs[t] = bias[t];

    const int wv = t >> 6, l = t & 63, lq = l >> 4, lm = l & 15;
    frag_cd acc[8];
#pragma unroll
    for (int tb = 0; tb < 8; ++tb) acc[tb] = (frag_cd){0.f, 0.f, 0.f, 0.f};

    for (int kt = 0; kt < K; kt += 64) {
        const unsigned short* Asrc = (kt < kSplit) ? A0 : A1;
        const int kcol = (kt < kSplit) ? kt : kt - kSplit;
#pragma unroll
        for (int p = 0; p < 2; ++p) {
            int idx = p * 256 + t;            // 512 uint4 = 64 x 64 bf16
            int row = idx >> 3, c4 = idx & 7;
            int gm = m0 + row;
            uint4 v = make_uint4(0, 0, 0, 0);
            if (gm < M) v = *(const uint4*)&Asrc[(size_t)gm * lda + kcol + c4 * 8];
            *(uint4*)&As[row][c4 * 8] = v;
        }
#pragma unroll
        for (int p = 0; p < 4; ++p) {
            int idx = p * 256 + t;            // 1024 uint4 = 128 x 64 bf16
            int n = idx >> 3, c4 = idx & 7;
            *(uint4*)&Ws[n][c4 * 8] = *(const uint4*)&Wt[(size_t)n * K + kt + c4 * 8];
        }
        __syncthreads();
#pragma unroll
        for (int kb = 0; kb < 2; ++kb) {
            frag_ab af = *(const frag_ab*)&As[wv * 16 + lm][kb * 32 + lq * 8];
#pragma unroll
            for (int tb = 0; tb < 8; ++tb) {
                frag_ab bf = *(const frag_ab*)&Ws[tb * 16 + lm][kb * 32 + lq * 8];
                acc[tb] = __builtin_amdgcn_mfma_f32_16x16x32_bf16(af, bf, acc[tb], 0, 0, 0);
            }
        }
        __syncthreads();
    }

    if constexpr (EPI == EPI_LAYER) {
        float sq[4] = {0.f, 0.f, 0.f, 0.f};
#pragma unroll
        for (int tb = 0; tb < 8; ++tb) {
            float b = bs[tb * 16 + lm];
#pragma unroll
            for (int r = 0; r < 4; ++r) {
                acc[tb][r] += b;
                sq[r] += acc[tb][r] * acc[tb][r];
            }
        }
#pragma unroll
        for (int r = 0; r < 4; ++r) part[wv * 16 + lq * 4 + r][lm] = sq[r];
        __syncthreads();
        if (t < 64) {
            float s = 0.f;
#pragma unroll
            for (int c = 0; c < 16; ++c) s += part[t][c];
            rinv[t] = 1.0f / fmaxf(sqrtf(s), 1e-12f);
        }
        __syncthreads();
#pragma unroll
        for (int r = 0; r < 4; ++r) {
            int gr = m0 + wv * 16 + lq * 4 + r;
            if (gr >= M) continue;
            float ri = rinv[wv * 16 + lq * 4 + r];
#pragma unroll
            for (int tb = 0; tb < 8; ++tb) {
                int col = tb * 16 + lm;
                float o = bfs(residbf[(size_t)gr * 128 + col]) +
                          fmaxf(acc[tb][r], 0.f) * ri;
                Cbf[(size_t)gr * 128 + col] = f2bf(o);
            }
        }
    } else {
#pragma unroll
        for (int r = 0; r < 4; ++r) {
            int gr = m0 + wv * 16 + lq * 4 + r;
            if (gr >= M) continue;
#pragma unroll
            for (int tb = 0; tb < 8; ++tb) {
                int col = tb * 16 + lm;
                Cbf[(size_t)gr * ldc + col] = f2bf(acc[tb][r] + bs[col]);
            }
        }
    }
}

// ---------------------------------------------------------------------------
// CSR construction (slim): deg -> scan -> fill writes ONLY srt via shifted-rp
// trick: pos = atomicAdd(&rp[d],1). After fill, rp[d] == end offset of d;
// agg uses [d ? rp[d-1] : 0, rp[d]).
// ---------------------------------------------------------------------------
__global__ void deg_k(const int* __restrict__ dst, int* __restrict__ deg) {
    int e = blockIdx.x * 256 + threadIdx.x;
    if (e < NE) atomicAdd(&deg[dst[e]], 1);
}

__global__ void scan1_k(const int* __restrict__ deg, int* __restrict__ rp,
                        int* __restrict__ bsum) {
    __shared__ int sh[512];
    int tid = threadIdx.x;
    int i = blockIdx.x * 512 + tid;
    int v = (i < NN) ? deg[i] : 0;
    sh[tid] = v;
    __syncthreads();
    for (int ofs = 1; ofs < 512; ofs <<= 1) {
        int x = (tid >= ofs) ? sh[tid - ofs] : 0;
        __syncthreads();
        sh[tid] += x;
        __syncthreads();
    }
    if (i < NN) rp[i] = sh[tid] - v;
    if (tid == 511) bsum[blockIdx.x] = sh[511];
}

__global__ void scan2_k(int* __restrict__ bsum, int nb) {
    __shared__ int sh[128];
    int tid = threadIdx.x;
    int v = (tid < nb) ? bsum[tid] : 0;
    sh[tid] = v;
    __syncthreads();
    for (int ofs = 1; ofs < 128; ofs <<= 1) {
        int x = (tid >= ofs) ? sh[tid - ofs] : 0;
        __syncthreads();
        sh[tid] += x;
        __syncthreads();
    }
    if (tid < nb) bsum[tid] = sh[tid] - v;
}

__global__ void scan3_k(int* __restrict__ rp, const int* __restrict__ bsum,
                        const int* __restrict__ deg, float* __restrict__ invd) {
    int i = blockIdx.x * 512 + threadIdx.x;
    if (i < NN) {
        rp[i] += bsum[blockIdx.x];
        int d = deg[i];
        invd[i] = 1.0f / (float)(d > 1 ? d : 1);
    }
}

__global__ void fill_k(const int* __restrict__ src, const int* __restrict__ dst,
                       int* __restrict__ rp, int* __restrict__ srt) {
    int e = blockIdx.x * 256 + threadIdx.x;
    if (e < NE) {
        int pos = atomicAdd(&rp[dst[e]], 1);
        srt[pos] = src[e];
    }
}

// ---------------------------------------------------------------------------
// Mean aggregation, one WAVE per node. 32 lanes x 8 B per row, wave halves
// alternate rows => 1 VMEM instr / 2 rows; 8-pair unroll => 16 rows in flight.
// Bounds from shifted rp: [gw ? rp[gw-1] : 0, rp[gw]).
// ---------------------------------------------------------------------------
__launch_bounds__(256, 8)
__global__ void agg_k(const unsigned short* __restrict__ hbf,
                      const int* __restrict__ rp, const int* __restrict__ srt,
                      const float* __restrict__ invd,
                      unsigned short* __restrict__ cbf) {
    int gw   = (blockIdx.x * 256 + threadIdx.x) >> 6;   // node = global wave id
    if (gw >= NN) return;
    const int lane = threadIdx.x & 63;
    const int half = lane >> 5;          // which neighbor of the pair
    const int hl   = lane & 31;          // feature group: 4 feats (8 B)
    const int b = gw ? rp[gw - 1] : 0;
    const int e = rp[gw];
    float a0 = 0.f, a1 = 0.f, a2 = 0.f, a3 = 0.f;

    int p = b;
    for (; p + 16 <= e; p += 16) {       // 8 pairs, 16 rows in flight
        int sidx[8];
#pragma unroll
        for (int u = 0; u < 8; ++u) sidx[u] = srt[p + u * 2 + half];
        uint2 uu[8];
#pragma unroll
        for (int u = 0; u < 8; ++u)
            uu[u] = *(const uint2*)&hbf[(size_t)sidx[u] * 128 + hl * 4];
#pragma unroll
        for (int u = 0; u < 8; ++u) {
            a0 += bflo(uu[u].x); a1 += bfhi(uu[u].x);
            a2 += bflo(uu[u].y); a3 += bfhi(uu[u].y);
        }
    }
    for (; p + 2 <= e; p += 2) {         // single pair
        int s = srt[p + half];
        uint2 u = *(const uint2*)&hbf[(size_t)s * 128 + hl * 4];
        a0 += bflo(u.x); a1 += bfhi(u.x);
        a2 += bflo(u.y); a3 += bfhi(u.y);
    }
    if (p < e && half == 0) {            // odd-degree tail (half 0 only)
        int s = srt[p];
        uint2 u = *(const uint2*)&hbf[(size_t)s * 128 + hl * 4];
        a0 += bflo(u.x); a1 += bfhi(u.x);
        a2 += bflo(u.y); a3 += bfhi(u.y);
    }
    // combine halves
    a0 += __shfl_xor(a0, 32, 64);
    a1 += __shfl_xor(a1, 32, 64);
    a2 += __shfl_xor(a2, 32, 64);
    a3 += __shfl_xor(a3, 32, 64);

    float iv = invd[gw];
    if (half == 0) {
        uint2 r = make_uint2(packbf(a0 * iv, a1 * iv), packbf(a2 * iv, a3 * iv));
        *(uint2*)&cbf[(size_t)gw * 128 + hl * 4] = r;
    }
}

// ---------------------------------------------------------------------------
// Prep (merged: x cast, weight transposes, deg zeroing).
// ---------------------------------------------------------------------------
constexpr int PREP_X    = 400000;                 // NN*64/8
constexpr int PREP_WCT  = PREP_X + 131072;
constexpr int PREP_WEFF = PREP_WCT + 32768;
constexpr int PREP_W1   = PREP_WEFF + 8192;
constexpr int PREP_BEFF = PREP_W1 + 256;
constexpr int PREP_WEMB = PREP_BEFF + 8192;
constexpr int PREP_DEG  = PREP_WEMB + NN;

__global__ void prep_k(const float* __restrict__ x, unsigned short* __restrict__ xbf,
                       const float* __restrict__ Wconv, const float* __restrict__ W0,
                       const float* __restrict__ b0, const float* __restrict__ W1,
                       const float* __restrict__ Wemb,
                       unsigned short* __restrict__ Wct,
                       unsigned short* __restrict__ Wefft,
                       float* __restrict__ beff, unsigned short* __restrict__ W1tg,
                       unsigned short* __restrict__ Wembt,
                       int* __restrict__ deg) {
    int i = blockIdx.x * 256 + threadIdx.x;
    if (i < PREP_X) {
        float4 a = *(const float4*)&x[(size_t)i * 8];
        float4 b = *(const float4*)&x[(size_t)i * 8 + 4];
        uint4 o = make_uint4(packbf(a.x, a.y), packbf(a.z, a.w),
                             packbf(b.x, b.y), packbf(b.z, b.w));
        *(uint4*)&xbf[(size_t)i * 8] = o;
    } else if (i < PREP_WCT) {
        int j = i - PREP_X;
        int lyr = j >> 15, r = j & 32767, n = r >> 8, k = r & 255;
        Wct[j] = f2bf(Wconv[(size_t)lyr * 32768 + k * 128 + n]);
    } else if (i < PREP_WEFF) {
        int j = i - PREP_WCT, n = j >> 7, k = j & 127;
        float v = (n < 128) ? W0[k * 128 + n] : W0[(128 + k) * 128 + (n - 128)];
        Wefft[j] = f2bf(v);
    } else if (i < PREP_W1) {
        int j = i - PREP_WEFF, n = j >> 7, k = j & 127;
        W1tg[j] = f2bf(W1[k * 64 + n]);
    } else if (i < PREP_BEFF) {
        int j = i - PREP_W1;
        beff[j] = (j < 128) ? b0[j] : 0.f;
    } else if (i < PREP_WEMB) {
        int j = i - PREP_BEFF, n = j >> 6, k = j & 63;
        Wembt[j] = f2bf(Wemb[k * 128 + n]);
    } else if (i < PREP_DEG) {
        deg[i - PREP_WEMB] = 0;
    }
}

// ---------------------------------------------------------------------------
// Fused edge readout (MFMA), ORIGINAL edge order (coalesced index reads &
// output stores), 64 edges/block, single barrier, in-register MLP2.
// LDS 35 KB -> 4 blocks/CU.
// ---------------------------------------------------------------------------
__launch_bounds__(256, 4)
__global__ void edge_mlp_k(const unsigned short* __restrict__ pq,
                           const int* __restrict__ esrc, const int* __restrict__ edst,
                           const unsigned short* __restrict__ W1tg,
                           const float* __restrict__ b1,
                           const float* __restrict__ W2, const float* __restrict__ b2,
                           float* __restrict__ out)
{
    __shared__ __align__(16) unsigned short E0s[64][136];  // 17408 B
    __shared__ __align__(16) unsigned short W1s[64][136];  // 17408 B
    const int t = threadIdx.x;
    const int e0 = blockIdx.x * 64;

    // stage W1: 64 rows x 128 ushorts = 1024 uint4 (4 per thread)
#pragma unroll
    for (int p = 0; p < 4; ++p) {
        int i4 = p * 256 + t;                 // 0..1023
        int row = i4 >> 4;                    // 16 uint4 per row
        int c4  = i4 & 15;
        *(uint4*)&W1s[row][c4 * 8] = ((const uint4*)W1tg)[i4];
    }

    // phase 1: e0 = relu(p[src] + q[dst]) -> E0s bf16 (4 threads/edge)
    {
        const int ei = t >> 2;
        const int fs = (t & 3) * 32;
        int s = esrc[e0 + ei];
        int d = edst[e0 + ei];
        const unsigned short* pr = pq + (size_t)s * 256 + fs;
        const unsigned short* qr = pq + (size_t)d * 256 + 128 + fs;
#pragma unroll
        for (int j = 0; j < 4; ++j) {
            uint4 a = *(const uint4*)(pr + j * 8);
            uint4 b = *(const uint4*)(qr + j * 8);
            uint4 r;
            r.x = packbf_fast(fmaxf(bflo(a.x) + bflo(b.x), 0.f),
                              fmaxf(bfhi(a.x) + bfhi(b.x), 0.f));
            r.y = packbf_fast(fmaxf(bflo(a.y) + bflo(b.y), 0.f),
                              fmaxf(bfhi(a.y) + bfhi(b.y), 0.f));
            r.z = packbf_fast(fmaxf(bflo(a.z) + bflo(b.z), 0.f),
                              fmaxf(bfhi(a.z) + bfhi(b.z), 0.f));
            r.w = packbf_fast(fmaxf(bflo(a.w) + bflo(b.w), 0.f),
                              fmaxf(bfhi(a.w) + bfhi(b.w), 0.f));
            *(uint4*)&E0s[ei][fs + j * 8] = r;
        }
    }
    __syncthreads();                 // single barrier

    // phase 2: MFMA. wave wv: edges [16wv,16wv+16) x 64 outs.
    const int wv = t >> 6, l = t & 63, lq = l >> 4, lm = l & 15;
    frag_cd acc[4];
#pragma unroll
    for (int tb = 0; tb < 4; ++tb) acc[tb] = (frag_cd){0.f, 0.f, 0.f, 0.f};
    const int erow = wv * 16 + lm;
#pragma unroll
    for (int kb = 0; kb < 4; ++kb) {
        frag_ab af = *(const frag_ab*)&E0s[erow][kb * 32 + lq * 8];
#pragma unroll
        for (int tb = 0; tb < 4; ++tb) {
            frag_ab bf = *(const frag_ab*)&W1s[tb * 16 + lm][kb * 32 + lq * 8];
            acc[tb] = __builtin_amdgcn_mfma_f32_16x16x32_bf16(af, bf, acc[tb], 0, 0, 0);
        }
    }

    // phase 3: in-register MLP2 (b1/W2 direct from global, L2-resident)
    float b1v[4], w20[4], w21[4];
#pragma unroll
    for (int tb = 0; tb < 4; ++tb) {
        int o = tb * 16 + lm;
        b1v[tb] = b1[o];
        w20[tb] = W2[o * 2];
        w21[tb] = W2[o * 2 + 1];
    }
    const float bo0 = b2[0], bo1 = b2[1];
#pragma unroll
    for (int r = 0; r < 4; ++r) {
        float s0 = 0.f, s1 = 0.f;
#pragma unroll
        for (int tb = 0; tb < 4; ++tb) {
            float e1 = fmaxf(acc[tb][r] + b1v[tb], 0.f);
            s0 += e1 * w20[tb];
            s1 += e1 * w21[tb];
        }
#pragma unroll
        for (int m = 1; m < 16; m <<= 1) {   // reduce over lm
            s0 += __shfl_xor(s0, m, 16);
            s1 += __shfl_xor(s1, m, 16);
        }
        if (lm == 0) {
            int e = wv * 16 + lq * 4 + r;
            *(float2*)&out[(size_t)(e0 + e) * 2] = make_float2(s0 + bo0, s1 + bo1);
        }
    }
}

// ---------------------------------------------------------------------------
extern "C" void kernel_launch(void* const* d_in, const int* in_sizes, int n_in,
                              void* d_out, int out_size, void* d_ws, size_t ws_size,
                              hipStream_t stream)
{
    const float* x    = (const float*)d_in[0];
    const int*   esrc = (const int*)  d_in[1];
    const int*   edst = (const int*)  d_in[2];
    const float* Wemb  = (const float*)d_in[5];
    const float* bemb  = (const float*)d_in[6];
    const float* Wconv = (const float*)d_in[7];
    const float* bconv = (const float*)d_in[8];
    const float* Wm0   = (const float*)d_in[9];
    const float* bm0   = (const float*)d_in[10];
    const float* Wm1   = (const float*)d_in[11];
    const float* bm1   = (const float*)d_in[12];
    const float* Wm2   = (const float*)d_in[13];
    const float* bm2   = (const float*)d_in[14];
    float* out = (float*)d_out;

    char* ws = (char*)d_ws;
    size_t off = 0;
    auto alloc = [&](size_t bytes) -> void* {
        void* p = ws + off;
        off = (off + bytes + 255) & ~(size_t)255;
        return p;
    };
    unsigned short* h0bf = (unsigned short*)alloc((size_t)NN * 128 * 2);
    unsigned short* h1bf = (unsigned short*)alloc((size_t)NN * 128 * 2);
    unsigned short* cbf  = (unsigned short*)alloc((size_t)NN * 128 * 2);
    unsigned short* pqb  = (unsigned short*)alloc((size_t)NN * 256 * 2);
    unsigned short* xbf  = (unsigned short*)alloc((size_t)NN * 64 * 2);
    unsigned short* Wct   = (unsigned short*)alloc(4 * 128 * 256 * 2);
    unsigned short* Wefft = (unsigned short*)alloc(256 * 128 * 2);
    float*          beff  = (float*)alloc(256 * 4);
    unsigned short* W1tg  = (unsigned short*)alloc(64 * 128 * 2);
    unsigned short* Wembt = (unsigned short*)alloc(128 * 64 * 2);
    int*   deg  = (int*)alloc((size_t)NN * 4);
    int*   rp   = (int*)alloc((size_t)(NN + 1) * 4);
    float* invd = (float*)alloc((size_t)NN * 4);
    int*   bsum = (int*)alloc(512);
    int*   srt  = (int*)alloc((size_t)NE * 4);
    (void)ws_size; (void)in_sizes; (void)n_in; (void)out_size;

    // cast + weight prep + deg zero (merged)
    prep_k<<<(PREP_DEG + 255) / 256, 256, 0, stream>>>(
        x, xbf, Wconv, Wm0, bm0, Wm1, Wemb, Wct, Wefft, beff, W1tg, Wembt, deg);

    // CSR build (slim: srt only, shifted-rp)
    deg_k  <<<(NE + 255) / 256, 256, 0, stream>>>(edst, deg);
    scan1_k<<<(NN + 511) / 512, 512, 0, stream>>>(deg, rp, bsum);
    scan2_k<<<1, 128, 0, stream>>>(bsum, (NN + 511) / 512);
    scan3_k<<<(NN + 511) / 512, 512, 0, stream>>>(rp, bsum, deg, invd);
    fill_k <<<(NE + 255) / 256, 256, 0, stream>>>(esrc, edst, rp, srt);

    // h0 = bf16(x @ Wemb + bemb) via MFMA
    mfma_gemm_k<EPI_PQBF><<<dim3((NN + 63) / 64, 1), 256, 0, stream>>>(
        xbf, nullptr, 64, 1 << 30, Wembt, bemb, h0bf, 128, nullptr, NN, 64);

    // 4 SAGE layers (MFMA, bf16 residual)
    unsigned short* hcbf = h0bf; unsigned short* hnbf = h1bf;
    for (int l = 0; l < 4; ++l) {
        agg_k<<<(NN + 3) / 4, 256, 0, stream>>>(hcbf, rp, srt, invd, cbf);
        mfma_gemm_k<EPI_LAYER><<<dim3((NN + 63) / 64, 1), 256, 0, stream>>>(
            hcbf, cbf, 128, 128, Wct + (size_t)l * 128 * 256,
            bconv + (size_t)l * 128, hnbf, 128, hcbf, NN, 256);
        unsigned short* tb = hcbf; hcbf = hnbf; hnbf = tb;
    }
    // after 4 layers: hcbf == h0bf

    // pq = bf16(h @ Weff + beff)  [NN][256]
    mfma_gemm_k<EPI_PQBF><<<dim3((NN + 63) / 64, 2), 256, 0, stream>>>(
        hcbf, nullptr, 128, 1 << 30, Wefft, beff, pqb, 256, nullptr, NN, 128);

    // fused edge readout (original order, single dispatch)
    edge_mlp_k<<<NE / 64, 256, 0, stream>>>(pqb, esrc, edst, W1tg, bm1, Wm2, bm2, out);
}